// Round 1
// 1955.734 us; speedup vs baseline: 2.0109x; 2.0109x over previous
//
#include <hip/hip_runtime.h>
#include <hip/hip_bf16.h>
#include <cstdint>

using bf16 = __hip_bfloat16;
using bf16x8 = __attribute__((ext_vector_type(8))) short;   // 8 bf16 = 4 VGPRs
using f32x4  = __attribute__((ext_vector_type(4))) float;

#define NHEADS 8
#define SEQ 49
#define CDIM 448
#define PDIM 1024
#define QS 40     // q/k LDS row stride, elems (20 dw; +4 banks/row -> 2-way max)
#define VTS 72    // vT row stride, elems (36 dw == 4 mod 32)
#define PS 72     // P row stride, elems
#define CS 136    // ctx row stride, elems (68 dw == 4 mod 32)

// ---------------- workspace layout (bf16 pre-converted inputs) ----------------
static constexpr size_t kNhs = (size_t)2048 * SEQ * CDIM;   // 44,957,696
static constexpr size_t kNqw = (size_t)1536 * CDIM;         // 688,128
static constexpr size_t kNqb = 1536;
static constexpr size_t kNpw = (size_t)CDIM * PDIM;         // 458,752
static constexpr size_t kNpb = CDIM;
static constexpr size_t kNab = NHEADS * SEQ;                // 392
static constexpr size_t OFF_HS = 64;                        // [0..3] = dtype flag
static constexpr size_t OFF_QW = OFF_HS + kNhs * 2;
static constexpr size_t OFF_QB = OFF_QW + kNqw * 2;
static constexpr size_t OFF_PW = OFF_QB + kNqb * 2;
static constexpr size_t OFF_PB = OFF_PW + kNpw * 2;
static constexpr size_t OFF_AB = OFF_PB + kNpb * 2;
static constexpr size_t WS_NEEDED = OFF_AB + kNab * 2;      // ~92.2 MB

__device__ __forceinline__ short f2s(float x) {
    union { bf16 h; short s; } u; u.h = __float2bfloat16(x); return u.s;
}
__device__ __forceinline__ bf16x8 load8(const bf16* p) { return *(const bf16x8*)p; }
__device__ __forceinline__ bf16x8 load8(const float* p) {
    f32x4 a = *(const f32x4*)p;
    f32x4 b = *(const f32x4*)(p + 4);
    bf16x8 r;
    r[0]=f2s(a[0]); r[1]=f2s(a[1]); r[2]=f2s(a[2]); r[3]=f2s(a[3]);
    r[4]=f2s(b[0]); r[5]=f2s(b[1]); r[6]=f2s(b[2]); r[7]=f2s(b[3]);
    return r;
}
__device__ __forceinline__ float toF(bf16 x) { return __bfloat162float(x); }
__device__ __forceinline__ float toF(float x) { return x; }
__device__ __forceinline__ void storeT(bf16* p, float v) { *p = __float2bfloat16(v); }
__device__ __forceinline__ void storeT(float* p, float v) { *p = v; }

// ---------------- fp32 -> bf16 pre-conversion (one pass over inputs) ----------
__device__ __forceinline__ void cvt_arr(const float* __restrict__ src,
                                        bf16* __restrict__ dst, size_t n4,
                                        size_t tid, size_t np) {
    for (size_t i = tid; i < n4; i += np) {
        f32x4 v = ((const f32x4*)src)[i];
        short4 o;
        o.x = f2s(v[0]); o.y = f2s(v[1]); o.z = f2s(v[2]); o.w = f2s(v[3]);
        ((short4*)dst)[i] = o;
    }
}

__global__ void convert_inputs(const float* hs, const float* qw, const float* qb,
                               const float* pw, const float* pb, const float* ab,
                               unsigned char* ws, const int* flag) {
    if (*flag == 0) return;   // inputs already bf16
    const size_t tid = (size_t)blockIdx.x * blockDim.x + threadIdx.x;
    const size_t np  = (size_t)gridDim.x * blockDim.x;
    cvt_arr(hs, (bf16*)(ws + OFF_HS), kNhs / 4, tid, np);
    cvt_arr(qw, (bf16*)(ws + OFF_QW), kNqw / 4, tid, np);
    cvt_arr(qb, (bf16*)(ws + OFF_QB), kNqb / 4, tid, np);
    cvt_arr(pw, (bf16*)(ws + OFF_PW), kNpw / 4, tid, np);
    cvt_arr(pb, (bf16*)(ws + OFF_PB), kNpb / 4, tid, np);
    cvt_arr(ab, (bf16*)(ws + OFF_AB), kNab / 4, tid, np);
}

// ---------------- fused attention body ----------------------------------------
// Per block: one batch. 4 waves. Per head:
//   A: QKV GEMM (MFMA, wave w owns 48 of 192 cols), epilogue scatters q,k (row-major)
//      and v TRANSPOSED (vT[d][token]) into LDS.          -> B1
//   B: scores = mfma(q,k) (wave w owns row-tile w), bias add, wave-parallel
//      softmax via shfl_xor in C-layout, P -> LDS bf16.   -> B2
//   C: PV = mfma(P, vT), ctx -> LDS bf16.                 -> B3
//   D: proj partial accumulate (persistent oacc), NO trailing barrier (next
//      head's conflicting LDS writes are gated by its own B1/B2).
template <typename T, typename TO>
__device__ __forceinline__
void body(const T* __restrict__ hs, const T* __restrict__ qkv_w,
          const T* __restrict__ qkv_b, const T* __restrict__ proj_w,
          const T* __restrict__ proj_b, const T* __restrict__ ab,
          const int* __restrict__ idx32, TO* __restrict__ out,
          bf16* ql, bf16* kl, bf16* vtl, bf16* pl, bf16* ctxl,
          float* abl, unsigned char* idx8) {
    const int b   = blockIdx.x;
    const int tid = threadIdx.x;
    const int l   = tid & 63;
    const int w   = tid >> 6;          // wave 0..3
    const int lr  = l & 15;            // A/B-operand row within 16
    const int lk  = (l >> 4) * 8;      // A/B-operand k offset
    const int cm  = (l >> 4) * 4;      // C/D row base
    const int cn  = l & 15;            // C/D col

    // idxs: dword1==1 -> int32; dword1==0 -> int64 (values<=48, high words 0)
    const int istr = (idx32[1] == 0) ? 2 : 1;
    for (int i = tid; i < NHEADS * SEQ; i += 256) abl[i] = toF(ab[i]);
    for (int i = tid; i < SEQ * SEQ; i += 256)
        idx8[i] = (unsigned char)idx32[i * istr];
    // zero vT pad tokens 49..63 ONCE (PV reads them with P=0; must be finite,
    // never overwritten afterwards since epilogue only writes tokens < 49)
    for (int i = tid; i < 128 * (64 - SEQ); i += 256) {
        const int d = i / (64 - SEQ), t = SEQ + i % (64 - SEQ);
        vtl[d * VTS + t] = __float2bfloat16(0.f);
    }

    f32x4 oacc[4][7] = {};   // persistent proj accumulator [mtile][ntile_j]
    const float scale = 0.17677669529663687f;  // 32^-0.5
    const T* hsb = hs + (size_t)b * SEQ * CDIM;

    for (int h = 0; h < NHEADS; ++h) {
        // ========= Phase A: QKV GEMM, wave w -> cols 48w..48w+47 of head chunk
        f32x4 qacc[3][4] = {};   // [j][mf]
        for (int ks = 0; ks < 14; ++ks) {
            const int k0 = ks * 32;
            bf16x8 af[4], bfr[3];
            #pragma unroll
            for (int mf = 0; mf < 4; ++mf) {
                int row = 16 * mf + lr; if (row > SEQ - 1) row = SEQ - 1;
                af[mf] = load8(hsb + row * CDIM + k0 + lk);
            }
            #pragma unroll
            for (int j = 0; j < 3; ++j) {
                const int n = h * 192 + (3 * w + j) * 16 + lr;
                bfr[j] = load8(qkv_w + (size_t)n * CDIM + k0 + lk);
            }
            #pragma unroll
            for (int j = 0; j < 3; ++j)
                #pragma unroll
                for (int mf = 0; mf < 4; ++mf)
                    qacc[j][mf] = __builtin_amdgcn_mfma_f32_16x16x32_bf16(
                        af[mf], bfr[j], qacc[j][mf], 0, 0, 0);
        }
        // epilogue: +bias; scatter q,k row-major; v TRANSPOSED -> vT[d][token]
        #pragma unroll
        for (int j = 0; j < 3; ++j) {
            const int c = (3 * w + j) * 16 + cn;              // 0..191
            const float bv = toF(qkv_b[h * 192 + c]);
            #pragma unroll
            for (int mf = 0; mf < 4; ++mf)
                #pragma unroll
                for (int r = 0; r < 4; ++r) {
                    const int row = 16 * mf + cm + r;          // token
                    const float v = qacc[j][mf][r] + bv;
                    if (row < SEQ) {
                        if (c < 32)      ql[row * QS + c] = __float2bfloat16(v);
                        else if (c < 64) kl[row * QS + (c - 32)] = __float2bfloat16(v);
                        else             vtl[(c - 64) * VTS + row] = __float2bfloat16(v);
                    }
                }
        }
        __syncthreads();   // B1: q/k/vT ready

        // ========= Phase B: scores MFMA + wave-parallel softmax + P(bf16)
        {
            const bf16x8 aq = *(const bf16x8*)(ql + (16 * w + lr) * QS + lk);
            f32x4 sacc[4] = {};
            #pragma unroll
            for (int j = 0; j < 4; ++j) {
                const bf16x8 kb = *(const bf16x8*)(kl + (16 * j + lr) * QS + lk);
                sacc[j] = __builtin_amdgcn_mfma_f32_16x16x32_bf16(
                    aq, kb, sacc[j], 0, 0, 0);
            }
            // C-layout: lane holds S[row=16w+cm+r][col=16j+cn]
            #pragma unroll
            for (int r = 0; r < 4; ++r) {
                const int row  = 16 * w + cm + r;
                const int ridx = (row < SEQ) ? row : 0;   // keep idx8 in-bounds
                float v[4], e[4];
                float m = -3.0e38f;
                #pragma unroll
                for (int j = 0; j < 4; ++j) {
                    const int col = 16 * j + cn;
                    if (col < SEQ) {
                        v[j] = sacc[j][r] * scale +
                               abl[h * SEQ + idx8[ridx * SEQ + col]];
                        m = fmaxf(m, v[j]);
                    } else v[j] = -3.0e38f;
                }
                m = fmaxf(m, __shfl_xor(m, 1));
                m = fmaxf(m, __shfl_xor(m, 2));
                m = fmaxf(m, __shfl_xor(m, 4));
                m = fmaxf(m, __shfl_xor(m, 8));
                float s = 0.f;
                #pragma unroll
                for (int j = 0; j < 4; ++j) {
                    e[j] = (16 * j + cn < SEQ) ? __expf(v[j] - m) : 0.f;
                    s += e[j];
                }
                s += __shfl_xor(s, 1);
                s += __shfl_xor(s, 2);
                s += __shfl_xor(s, 4);
                s += __shfl_xor(s, 8);
                const float inv = 1.f / s;
                #pragma unroll
                for (int j = 0; j < 4; ++j)
                    pl[row * PS + 16 * j + cn] = __float2bfloat16(e[j] * inv);
            }
        }
        __syncthreads();   // B2: P ready

        // ========= Phase C: PV MFMA, wave w -> row-tile w, ctx[64x128]
        {
            f32x4 cacc[8] = {};
            #pragma unroll
            for (int ks = 0; ks < 2; ++ks) {
                const bf16x8 pa =
                    *(const bf16x8*)(pl + (16 * w + lr) * PS + ks * 32 + lk);
                #pragma unroll
                for (int n = 0; n < 8; ++n) {
                    const bf16x8 vb =
                        *(const bf16x8*)(vtl + (16 * n + lr) * VTS + ks * 32 + lk);
                    cacc[n] = __builtin_amdgcn_mfma_f32_16x16x32_bf16(
                        pa, vb, cacc[n], 0, 0, 0);
                }
            }
            #pragma unroll
            for (int n = 0; n < 8; ++n)
                #pragma unroll
                for (int r = 0; r < 4; ++r)
                    ctxl[(16 * w + cm + r) * CS + 16 * n + cn] =
                        __float2bfloat16(cacc[n][r]);
        }
        __syncthreads();   // B3: ctx ready

        // ========= Phase D: proj partial (MFMA): oacc += ctx_h @ proj_w_h^T
        #pragma unroll
        for (int ks3 = 0; ks3 < 4; ++ks3) {
            bf16x8 ac[4], bw[7];
            #pragma unroll
            for (int mf = 0; mf < 4; ++mf)
                ac[mf] = *(const bf16x8*)(ctxl + (16 * mf + lr) * CS + ks3 * 32 + lk);
            #pragma unroll
            for (int j = 0; j < 7; ++j) {
                const int n = (w * 7 + j) * 16 + lr;
                bw[j] = load8(proj_w + (size_t)n * PDIM + h * 128 + ks3 * 32 + lk);
            }
            #pragma unroll
            for (int mf = 0; mf < 4; ++mf)
                #pragma unroll
                for (int j = 0; j < 7; ++j)
                    oacc[mf][j] = __builtin_amdgcn_mfma_f32_16x16x32_bf16(
                        ac[mf], bw[j], oacc[mf][j], 0, 0, 0);
        }
        // no barrier: next head's phase-A epilogue only writes ql/kl/vtl, whose
        // last readers (phase B/C) finished before B3; laggards here read only
        // ctxl/proj_w, and next-head pl/ctxl writes are gated by next B1/B2.
    }

    // ========= store: out[b*49+row][col] = oacc + proj_b
    #pragma unroll
    for (int j = 0; j < 7; ++j) {
        const int col = w * 112 + j * 16 + cn;
        const float pbv = toF(proj_b[col]);
        #pragma unroll
        for (int mf = 0; mf < 4; ++mf)
            #pragma unroll
            for (int r = 0; r < 4; ++r) {
                const int row = 16 * mf + cm + r;
                if (row < SEQ)
                    storeT(out + ((size_t)b * SEQ + row) * CDIM + col,
                           oacc[mf][j][r] + pbv);
            }
    }
}

// dtype detector: low 16 bits of fp32 dwords are uniform mantissa bits; for bf16
// data they're a bf16 value with exponent in the small-value window.
__global__ void detect_dtype(const unsigned int* __restrict__ w, int* __restrict__ flag) {
    if (threadIdx.x == 0 && blockIdx.x == 0) {
        int cnt = 0;
        for (int i = 0; i < 256; ++i) {
            const unsigned e = (w[i] >> 7) & 0xFF;
            cnt += (e >= 0x40 && e <= 0x7D);
        }
        *flag = (cnt < 156) ? 1 : 0;   // 1 = fp32, 0 = bf16
    }
}

__global__ __launch_bounds__(256, 2)
void fused_effattn(const void* hs, const void* qkv_w, const void* qkv_b,
                   const void* proj_w, const void* proj_b, const void* ab,
                   const int* idxs, void* out, unsigned char* ws, int use_ws) {
    __shared__ __align__(16) bf16 ql[64 * QS];
    __shared__ __align__(16) bf16 kl[64 * QS];
    __shared__ __align__(16) bf16 vtl[128 * VTS];
    __shared__ __align__(16) bf16 pl[64 * PS];
    __shared__ __align__(16) bf16 ctxl[64 * CS];
    __shared__ float abl[NHEADS * SEQ];
    __shared__ unsigned char idx8[SEQ * SEQ];

    const int f = *(const int*)ws;
    if (f) {
        if (use_ws) {
            body<bf16, float>((const bf16*)(ws + OFF_HS), (const bf16*)(ws + OFF_QW),
                              (const bf16*)(ws + OFF_QB), (const bf16*)(ws + OFF_PW),
                              (const bf16*)(ws + OFF_PB), (const bf16*)(ws + OFF_AB),
                              idxs, (float*)out, ql, kl, vtl, pl, ctxl, abl, idx8);
        } else {
            body<float, float>((const float*)hs, (const float*)qkv_w,
                               (const float*)qkv_b, (const float*)proj_w,
                               (const float*)proj_b, (const float*)ab,
                               idxs, (float*)out, ql, kl, vtl, pl, ctxl, abl, idx8);
        }
    } else {
        body<bf16, bf16>((const bf16*)hs, (const bf16*)qkv_w, (const bf16*)qkv_b,
                         (const bf16*)proj_w, (const bf16*)proj_b, (const bf16*)ab,
                         idxs, (bf16*)out, ql, kl, vtl, pl, ctxl, abl, idx8);
    }
}

extern "C" void kernel_launch(void* const* d_in, const int* in_sizes, int n_in,
                              void* d_out, int out_size, void* d_ws, size_t ws_size,
                              hipStream_t stream) {
    unsigned char* ws = (unsigned char*)d_ws;
    detect_dtype<<<1, 64, 0, stream>>>((const unsigned int*)d_in[1], (int*)ws);
    const int use_ws = (ws_size >= WS_NEEDED) ? 1 : 0;
    if (use_ws)
        convert_inputs<<<dim3(2048), dim3(256), 0, stream>>>(
            (const float*)d_in[0], (const float*)d_in[1], (const float*)d_in[2],
            (const float*)d_in[3], (const float*)d_in[4], (const float*)d_in[5],
            ws, (const int*)ws);
    fused_effattn<<<dim3(2048), dim3(256), 0, stream>>>(
        d_in[0], d_in[1], d_in[2], d_in[3], d_in[4], d_in[5],
        (const int*)d_in[6], d_out, ws, use_ws);
}

// Round 2
// 1519.186 us; speedup vs baseline: 2.5888x; 1.2874x over previous
//
#include <hip/hip_runtime.h>
#include <hip/hip_bf16.h>
#include <cstdint>

using bf16 = __hip_bfloat16;
using bf16x8 = __attribute__((ext_vector_type(8))) short;   // 8 bf16 = 4 VGPRs
using f32x4  = __attribute__((ext_vector_type(4))) float;

#define NHEADS 8
#define SEQ 49
#define CDIM 448
#define PDIM 1024
#define QS 36     // q/k LDS row stride, elems (18 dw; 18*r mod 32 distinct -> 2-way max)
#define VTS 68    // vT row stride, elems (34 dw == 2 mod 32 -> 2-way)
#define CS 132    // ctx row stride, elems (66 dw == 2 mod 32 -> 2-way); P aliased in cols 0..63

// ---------------- LDS layout (all offsets 16B aligned) ------------------------
static constexpr int SM_CTX = 0;                 // 64*132*2 = 16896 (P tile aliased per wave)
static constexpr int SM_QL  = 16896;             // 64*36*2  = 4608
static constexpr int SM_KL  = 21504;             // 4608
static constexpr int SM_VT  = 26112;             // 128*68*2 = 17408
static constexpr int SM_AB  = 43520;             // 392*4    = 1568
static constexpr int SM_SZ  = 45088;

// ---------------- workspace layout (bf16 pre-converted inputs) ----------------
static constexpr size_t kNhs = (size_t)2048 * SEQ * CDIM;   // 44,957,696
static constexpr size_t kNqw = (size_t)1536 * CDIM;         // 688,128
static constexpr size_t kNqb = 1536;
static constexpr size_t kNpw = (size_t)CDIM * PDIM;         // 458,752
static constexpr size_t kNpb = CDIM;
static constexpr size_t kNab = NHEADS * SEQ;                // 392
static constexpr size_t OFF_HS = 64;                        // [0..3] = dtype flag
static constexpr size_t OFF_QW = OFF_HS + kNhs * 2;
static constexpr size_t OFF_QB = OFF_QW + kNqw * 2;
static constexpr size_t OFF_PW = OFF_QB + kNqb * 2;
static constexpr size_t OFF_PB = OFF_PW + kNpw * 2;
static constexpr size_t OFF_AB = OFF_PB + kNpb * 2;
static constexpr size_t WS_NEEDED = OFF_AB + kNab * 2;      // ~92.2 MB

__device__ __forceinline__ short f2s(float x) {
    union { bf16 h; short s; } u; u.h = __float2bfloat16(x); return u.s;
}
__device__ __forceinline__ bf16x8 load8(const bf16* p) { return *(const bf16x8*)p; }
__device__ __forceinline__ bf16x8 load8(const float* p) {
    f32x4 a = *(const f32x4*)p;
    f32x4 b = *(const f32x4*)(p + 4);
    bf16x8 r;
    r[0]=f2s(a[0]); r[1]=f2s(a[1]); r[2]=f2s(a[2]); r[3]=f2s(a[3]);
    r[4]=f2s(b[0]); r[5]=f2s(b[1]); r[6]=f2s(b[2]); r[7]=f2s(b[3]);
    return r;
}
__device__ __forceinline__ float toF(bf16 x) { return __bfloat162float(x); }
__device__ __forceinline__ float toF(float x) { return x; }
__device__ __forceinline__ void storeT(bf16* p, float v) { *p = __float2bfloat16(v); }
__device__ __forceinline__ void storeT(float* p, float v) { *p = v; }

// ---------------- fp32 -> bf16 pre-conversion (one pass over inputs) ----------
__device__ __forceinline__ void cvt_arr(const float* __restrict__ src,
                                        bf16* __restrict__ dst, size_t n4,
                                        size_t tid, size_t np) {
    for (size_t i = tid; i < n4; i += np) {
        f32x4 v = ((const f32x4*)src)[i];
        short4 o;
        o.x = f2s(v[0]); o.y = f2s(v[1]); o.z = f2s(v[2]); o.w = f2s(v[3]);
        ((short4*)dst)[i] = o;
    }
}

__global__ void convert_inputs(const float* hs, const float* qw, const float* qb,
                               const float* pw, const float* pb, const float* ab,
                               unsigned char* ws, const int* flag) {
    if (*flag == 0) return;   // inputs already bf16
    const size_t tid = (size_t)blockIdx.x * blockDim.x + threadIdx.x;
    const size_t np  = (size_t)gridDim.x * blockDim.x;
    cvt_arr(hs, (bf16*)(ws + OFF_HS), kNhs / 4, tid, np);
    cvt_arr(qw, (bf16*)(ws + OFF_QW), kNqw / 4, tid, np);
    cvt_arr(qb, (bf16*)(ws + OFF_QB), kNqb / 4, tid, np);
    cvt_arr(pw, (bf16*)(ws + OFF_PW), kNpw / 4, tid, np);
    cvt_arr(pb, (bf16*)(ws + OFF_PB), kNpb / 4, tid, np);
    cvt_arr(ab, (bf16*)(ws + OFF_AB), kNab / 4, tid, np);
}

// ---------------- fused attention body ----------------------------------------
// Per block: one batch, 4 waves, 2 barriers per head:
//   A: QKV GEMM (2-deep reg-pipelined); epilogue scatters q,k row-major and
//      v transposed.                                     -> B1
//   B: scores MFMA + bias (computed idx) + wave-parallel softmax; P(bf16) is
//      written into the wave's OWN ctx-tile rows (cols 0..63) — no barrier
//      (in-wave write->read only).
//   C: PV MFMA: reads own P rows + all vT; overwrites own ctx-tile rows with
//      ctx values (pa fragments read before any write).  -> B3
//   D: proj partial accumulate into persistent oacc (reads all ctx rows +
//      global proj_w). No trailing barrier: next head's B1 orders everything
//      (slow waves can't be overtaken past a barrier).
template <typename T, typename TO>
__device__ __forceinline__
void body(const T* __restrict__ hs, const T* __restrict__ qkv_w,
          const T* __restrict__ qkv_b, const T* __restrict__ proj_w,
          const T* __restrict__ proj_b, const T* __restrict__ ab,
          TO* __restrict__ out, char* smem) {
    bf16*  ctxp = (bf16*)(smem + SM_CTX);
    bf16*  ql   = (bf16*)(smem + SM_QL);
    bf16*  kl   = (bf16*)(smem + SM_KL);
    bf16*  vtl  = (bf16*)(smem + SM_VT);
    float* abl  = (float*)(smem + SM_AB);

    const int b   = blockIdx.x;
    const int tid = threadIdx.x;
    const int l   = tid & 63;
    const int w   = tid >> 6;          // wave 0..3
    const int lr  = l & 15;            // A/B-operand row within 16
    const int lk  = (l >> 4) * 8;      // A/B-operand k offset
    const int cm  = (l >> 4) * 4;      // C/D row base
    const int cn  = l & 15;            // C/D col

    for (int i = tid; i < NHEADS * SEQ; i += 256) abl[i] = toF(ab[i]);
    // zero vT pad tokens 49..63 once (PV reads them with P=0; never overwritten)
    for (int i = tid; i < 128 * (64 - SEQ); i += 256) {
        const int d = i / (64 - SEQ), t = SEQ + i % (64 - SEQ);
        vtl[d * VTS + t] = __float2bfloat16(0.f);
    }

    // bias index precompute: idx(r1,c1,r2,c2) = |r1-r2|*7 + |c1-c2|, token t=(t/7,t%7)
    int rq[4], rr[4], cq[4], cr[4];
    #pragma unroll
    for (int r = 0; r < 4; ++r) {
        int row = 16 * w + cm + r; if (row > SEQ - 1) row = SEQ - 1;
        rq[r] = (row * 37) >> 8; rr[r] = row - rq[r] * 7;
    }
    #pragma unroll
    for (int j = 0; j < 4; ++j) {
        int col = 16 * j + cn; if (col > SEQ - 1) col = 0;   // pad cols unused
        cq[j] = (col * 37) >> 8; cr[j] = col - cq[j] * 7;
    }

    f32x4 oacc[4][7] = {};   // persistent proj accumulator [mtile][ntile_j]
    const float scale = 0.17677669529663687f;  // 32^-0.5
    const T* hsb = hs + (size_t)b * SEQ * CDIM;

    for (int h = 0; h < NHEADS; ++h) {
        // ========= Phase A: QKV GEMM, wave w -> cols 48w..48w+47, 2-deep pipeline
        f32x4 qacc[3][4] = {};   // [j][mf]
        bf16x8 af0[4], bf0[3], af1[4], bf1[3];

        auto LOADA = [&](int ks, bf16x8* af, bf16x8* bfr) {
            const int k0 = ks * 32;
            #pragma unroll
            for (int mf = 0; mf < 4; ++mf) {
                int row = 16 * mf + lr; if (row > SEQ - 1) row = SEQ - 1;
                af[mf] = load8(hsb + row * CDIM + k0 + lk);
            }
            #pragma unroll
            for (int j = 0; j < 3; ++j) {
                const int n = h * 192 + (3 * w + j) * 16 + lr;
                bfr[j] = load8(qkv_w + (size_t)n * CDIM + k0 + lk);
            }
        };
        auto MFMAA = [&](bf16x8* af, bf16x8* bfr) {
            #pragma unroll
            for (int j = 0; j < 3; ++j)
                #pragma unroll
                for (int mf = 0; mf < 4; ++mf)
                    qacc[j][mf] = __builtin_amdgcn_mfma_f32_16x16x32_bf16(
                        af[mf], bfr[j], qacc[j][mf], 0, 0, 0);
        };

        LOADA(0, af0, bf0);
        LOADA(1, af1, bf1);
        #pragma unroll
        for (int ks = 0; ks < 14; ks += 2) {
            MFMAA(af0, bf0);
            if (ks + 2 < 14) LOADA(ks + 2, af0, bf0);
            MFMAA(af1, bf1);
            if (ks + 3 < 14) LOADA(ks + 3, af1, bf1);
        }

        // epilogue: +bias; scatter q,k row-major; v TRANSPOSED -> vT[d][token]
        #pragma unroll
        for (int j = 0; j < 3; ++j) {
            const int c = (3 * w + j) * 16 + cn;              // 0..191
            const float bv = toF(qkv_b[h * 192 + c]);
            #pragma unroll
            for (int mf = 0; mf < 4; ++mf)
                #pragma unroll
                for (int r = 0; r < 4; ++r) {
                    const int row = 16 * mf + cm + r;          // token
                    const float v = qacc[j][mf][r] + bv;
                    if (row < SEQ) {
                        if (c < 32)      ql[row * QS + c] = __float2bfloat16(v);
                        else if (c < 64) kl[row * QS + (c - 32)] = __float2bfloat16(v);
                        else             vtl[(c - 64) * VTS + row] = __float2bfloat16(v);
                    }
                }
        }
        __syncthreads();   // B1: q/k/vT ready (also orders prev head's D vs our writes)

        // ========= Phase B: scores MFMA + softmax; P -> own ctx-tile rows (no barrier)
        {
            const bf16x8 aq = *(const bf16x8*)(ql + (16 * w + lr) * QS + lk);
            f32x4 sacc[4] = {};
            #pragma unroll
            for (int j = 0; j < 4; ++j) {
                const bf16x8 kb = *(const bf16x8*)(kl + (16 * j + lr) * QS + lk);
                sacc[j] = __builtin_amdgcn_mfma_f32_16x16x32_bf16(
                    aq, kb, sacc[j], 0, 0, 0);
            }
            // C-layout: lane holds S[row=16w+cm+r][col=16j+cn]
            #pragma unroll
            for (int r = 0; r < 4; ++r) {
                const int row = 16 * w + cm + r;
                float v[4], e[4];
                float m = -3.0e38f;
                #pragma unroll
                for (int j = 0; j < 4; ++j) {
                    const int col = 16 * j + cn;
                    if (col < SEQ) {
                        int dy = rq[r] - cq[j]; dy = dy < 0 ? -dy : dy;
                        int dx = rr[r] - cr[j]; dx = dx < 0 ? -dx : dx;
                        v[j] = sacc[j][r] * scale + abl[h * SEQ + dy * 7 + dx];
                        m = fmaxf(m, v[j]);
                    } else v[j] = -3.0e38f;
                }
                m = fmaxf(m, __shfl_xor(m, 1));
                m = fmaxf(m, __shfl_xor(m, 2));
                m = fmaxf(m, __shfl_xor(m, 4));
                m = fmaxf(m, __shfl_xor(m, 8));
                float s = 0.f;
                #pragma unroll
                for (int j = 0; j < 4; ++j) {
                    e[j] = (16 * j + cn < SEQ) ? __expf(v[j] - m) : 0.f;
                    s += e[j];
                }
                s += __shfl_xor(s, 1);
                s += __shfl_xor(s, 2);
                s += __shfl_xor(s, 4);
                s += __shfl_xor(s, 8);
                const float inv = 1.f / s;
                #pragma unroll
                for (int j = 0; j < 4; ++j)
                    ctxp[row * CS + 16 * j + cn] = __float2bfloat16(e[j] * inv);
            }
        }
        // no barrier: wave w wrote P only into its own rows 16w..16w+15

        // ========= Phase C: PV MFMA (reads own P + all vT), overwrite own ctx rows
        {
            // read BOTH P fragments before any ctx write (anti-dep, in-wave)
            const bf16x8 pa0 = *(const bf16x8*)(ctxp + (16 * w + lr) * CS + lk);
            const bf16x8 pa1 = *(const bf16x8*)(ctxp + (16 * w + lr) * CS + 32 + lk);
            f32x4 cacc[8] = {};
            #pragma unroll
            for (int n = 0; n < 8; ++n) {
                const bf16x8 vb0 = *(const bf16x8*)(vtl + (16 * n + lr) * VTS + lk);
                cacc[n] = __builtin_amdgcn_mfma_f32_16x16x32_bf16(
                    pa0, vb0, cacc[n], 0, 0, 0);
            }
            #pragma unroll
            for (int n = 0; n < 8; ++n) {
                const bf16x8 vb1 = *(const bf16x8*)(vtl + (16 * n + lr) * VTS + 32 + lk);
                cacc[n] = __builtin_amdgcn_mfma_f32_16x16x32_bf16(
                    pa1, vb1, cacc[n], 0, 0, 0);
            }
            #pragma unroll
            for (int n = 0; n < 8; ++n)
                #pragma unroll
                for (int r = 0; r < 4; ++r)
                    ctxp[(16 * w + cm + r) * CS + 16 * n + cn] =
                        __float2bfloat16(cacc[n][r]);
        }
        __syncthreads();   // B3: ctx ready for cross-wave proj reads

        // ========= Phase D: proj partial (MFMA): oacc += ctx_h @ proj_w_h^T
        #pragma unroll
        for (int ks3 = 0; ks3 < 4; ++ks3) {
            bf16x8 bw[7], ac[4];
            #pragma unroll
            for (int j = 0; j < 7; ++j) {
                const int n = (w * 7 + j) * 16 + lr;
                bw[j] = load8(proj_w + (size_t)n * PDIM + h * 128 + ks3 * 32 + lk);
            }
            #pragma unroll
            for (int mf = 0; mf < 4; ++mf)
                ac[mf] = *(const bf16x8*)(ctxp + (16 * mf + lr) * CS + ks3 * 32 + lk);
            #pragma unroll
            for (int mf = 0; mf < 4; ++mf)
                #pragma unroll
                for (int j = 0; j < 7; ++j)
                    oacc[mf][j] = __builtin_amdgcn_mfma_f32_16x16x32_bf16(
                        ac[mf], bw[j], oacc[mf][j], 0, 0, 0);
        }
        // no barrier: next head's B1 orders slow-wave D reads vs fast-wave writes
    }

    // ========= store: out[b*49+row][col] = oacc + proj_b
    #pragma unroll
    for (int j = 0; j < 7; ++j) {
        const int col = w * 112 + j * 16 + cn;
        const float pbv = toF(proj_b[col]);
        #pragma unroll
        for (int mf = 0; mf < 4; ++mf)
            #pragma unroll
            for (int r = 0; r < 4; ++r) {
                const int row = 16 * mf + cm + r;
                if (row < SEQ)
                    storeT(out + ((size_t)b * SEQ + row) * CDIM + col,
                           oacc[mf][j][r] + pbv);
            }
    }
}

// dtype detector: low 16 bits of fp32 dwords are uniform mantissa bits; for bf16
// data they're a bf16 value with exponent in the small-value window.
__global__ void detect_dtype(const unsigned int* __restrict__ w, int* __restrict__ flag) {
    if (threadIdx.x == 0 && blockIdx.x == 0) {
        int cnt = 0;
        for (int i = 0; i < 256; ++i) {
            const unsigned e = (w[i] >> 7) & 0xFF;
            cnt += (e >= 0x40 && e <= 0x7D);
        }
        *flag = (cnt < 156) ? 1 : 0;   // 1 = fp32, 0 = bf16
    }
}

__global__ __launch_bounds__(256, 2)
void fused_effattn(const void* hs, const void* qkv_w, const void* qkv_b,
                   const void* proj_w, const void* proj_b, const void* ab,
                   const int* idxs, void* out, unsigned char* ws, int use_ws) {
    __shared__ __align__(16) char smem[SM_SZ];

    const int f = *(const int*)ws;
    if (f) {
        if (use_ws) {
            body<bf16, float>((const bf16*)(ws + OFF_HS), (const bf16*)(ws + OFF_QW),
                              (const bf16*)(ws + OFF_QB), (const bf16*)(ws + OFF_PW),
                              (const bf16*)(ws + OFF_PB), (const bf16*)(ws + OFF_AB),
                              (float*)out, smem);
        } else {
            body<float, float>((const float*)hs, (const float*)qkv_w,
                               (const float*)qkv_b, (const float*)proj_w,
                               (const float*)proj_b, (const float*)ab,
                               (float*)out, smem);
        }
    } else {
        body<bf16, bf16>((const bf16*)hs, (const bf16*)qkv_w, (const bf16*)qkv_b,
                         (const bf16*)proj_w, (const bf16*)proj_b, (const bf16*)ab,
                         (bf16*)out, smem);
    }
}

extern "C" void kernel_launch(void* const* d_in, const int* in_sizes, int n_in,
                              void* d_out, int out_size, void* d_ws, size_t ws_size,
                              hipStream_t stream) {
    unsigned char* ws = (unsigned char*)d_ws;
    detect_dtype<<<1, 64, 0, stream>>>((const unsigned int*)d_in[1], (int*)ws);
    const int use_ws = (ws_size >= WS_NEEDED) ? 1 : 0;
    if (use_ws)
        convert_inputs<<<dim3(2048), dim3(256), 0, stream>>>(
            (const float*)d_in[0], (const float*)d_in[1], (const float*)d_in[2],
            (const float*)d_in[3], (const float*)d_in[4], (const float*)d_in[5],
            ws, (const int*)ws);
    fused_effattn<<<dim3(2048), dim3(256), 0, stream>>>(
        d_in[0], d_in[1], d_in[2], d_in[3], d_in[4], d_in[5],
        (const int*)d_in[6], d_out, ws, use_ws);
}